// Round 2
// baseline (10564.870 us; speedup 1.0000x reference)
//
#include <hip/hip_runtime.h>
#include <math.h>

// Problem constants
#define NWG    48       // workgroups = 768/EC ; all co-resident
#define TT     1024     // timesteps per layer
#define BSZ    16       // batch
#define DHH    768      // hidden dim
#define NGG    4        // gates
#define EC     16       // e-chunk per WG
#define KSPLIT 192      // K range per wave (768/4)
#define PPITCH 20       // partial-sum pitch (dwords): 16B-aligned, 2-way banks max

typedef __attribute__((ext_vector_type(8))) short bf16x8_t;  // MFMA A/B frag
typedef __attribute__((ext_vector_type(4))) float f32x4_t;   // MFMA C/D frag

__device__ __forceinline__ unsigned short f2bf(float f) {
  union { float f; unsigned int u; } v; v.f = f;
  return (unsigned short)((v.u + 0x7fffu + ((v.u >> 16) & 1u)) >> 16);  // RNE
}

__global__ void lstm_init_ws(int* cnt) {
  if (threadIdx.x < 4) cnt[threadIdx.x * 32] = 0;   // 4 sharded arrival counters
}

__global__ __launch_bounds__(256, 1) void lstm_persistent(
    const float* __restrict__ states,
    const float* __restrict__ Wx0, const float* __restrict__ R0, const float* __restrict__ b0,
    const float* __restrict__ Wx1, const float* __restrict__ R1, const float* __restrict__ b1,
    float* __restrict__ out, int* __restrict__ cnt, unsigned short* __restrict__ hbuf)
{
  // partial gate sums: [w=4][g=4][m(e)=16][q*4+r(batch), pitch 20] = 20 KB
  __shared__ __align__(16) float pg[NGG * 4 * BSZ * PPITCH];

  const int tid  = threadIdx.x;
  const int lane = tid & 63;
  const int wv   = tid >> 6;    // wave id: K-range owner
  const int bb   = tid >> 4;    // batch row for elementwise (256 = 16*16)
  const int el   = tid & 15;    // local e for elementwise
  const int e0   = blockIdx.x * EC;
  const int m    = lane & 15;   // MFMA: A-row(batch) / B-col(e) / D-col
  const int q    = lane >> 4;   // MFMA quad

  // ---- thread-private persistent state: cell c for (bb, e0+el)
  float c = states[(BSZ + bb) * DHH + e0 + el];
  hbuf[bb * DHH + e0 + el] = f2bf(states[bb * DHH + e0 + el]);  // h0 (bf16) broadcast slice

  int target = NWG;
  __syncthreads();  // drains vmem before barrier
  if (wv == 0) {
    if (lane == 0)
      __hip_atomic_fetch_add(&cnt[(blockIdx.x & 3) * 32], 1, __ATOMIC_RELEASE, __HIP_MEMORY_SCOPE_AGENT);
    int total = 0;
    do {
      int v = (lane < 4) ? __hip_atomic_load(&cnt[lane * 32], __ATOMIC_RELAXED, __HIP_MEMORY_SCOPE_AGENT) : 0;
      v += __shfl_xor(v, 1);
      v += __shfl_xor(v, 2);
      total = __shfl(v, 0);
    } while (total < target);
    __builtin_amdgcn_fence(__ATOMIC_ACQUIRE, "agent");
  }
  __syncthreads();

  for (int layer = 0; layer < 2; ++layer) {
    const float* Wx = layer ? Wx1 : Wx0;
    const float* Rm = layer ? R1  : R0;
    const float* bv = layer ? b1  : b0;

    // per-thread bias (elementwise role), registers
    float bias[NGG];
    #pragma unroll
    for (int g = 0; g < NGG; ++g) bias[g] = bv[g * DHH + e0 + el];

    // B fragments -> registers, once per layer. Wave wv owns K in [wv*192, wv*192+192).
    // Frag for (g, k0): lane(q,m) holds B[k = wv*192 + k0*32 + q*8 + j][n = e0+m], j=0..7
    bf16x8_t Bfr[NGG][6];
    #pragma unroll
    for (int g = 0; g < NGG; ++g) {
      #pragma unroll
      for (int k0 = 0; k0 < 6; ++k0) {
        const float* rp = Rm + (size_t)(g * DHH + wv * KSPLIT + k0 * 32 + q * 8) * DHH + e0 + m;
        bf16x8_t f;
        #pragma unroll
        for (int j = 0; j < 8; ++j) f[j] = (short)f2bf(rp[j * DHH]);
        Bfr[g][k0] = f;
      }
    }

    for (int t = 0; t < TT; ++t) {
      const int gs = layer * TT + t;
      const unsigned short* __restrict__ hsrc = hbuf + (gs & 1) * (BSZ * DHH);
      unsigned short* __restrict__ hdst = hbuf + ((gs + 1) & 1) * (BSZ * DHH);

      // Wx for this step (consumed post-sync; ~full MFMA phase to hide HBM latency)
      const float* wxp = Wx + ((size_t)(bb * TT + t) * NGG) * DHH + e0 + el;
      const float wxv0 = wxp[0];
      const float wxv1 = wxp[DHH];
      const float wxv2 = wxp[2 * DHH];
      const float wxv3 = wxp[3 * DHH];

      // A fragments straight from global (IF$/L2), no LDS staging:
      // lane(q,m): A[m][k = wv*192 + k0*32 + q*8 + j]
      {
        const unsigned short* hp = hsrc + m * DHH + wv * KSPLIT + q * 8;
        bf16x8_t A[6];
        #pragma unroll
        for (int k0 = 0; k0 < 6; ++k0) A[k0] = *(const bf16x8_t*)(hp + k0 * 32);

        f32x4_t a0 = {0.f,0.f,0.f,0.f}, a1 = {0.f,0.f,0.f,0.f};
        f32x4_t a2 = {0.f,0.f,0.f,0.f}, a3 = {0.f,0.f,0.f,0.f};
        #pragma unroll
        for (int k0 = 0; k0 < 6; ++k0) {
          a0 = __builtin_amdgcn_mfma_f32_16x16x32_bf16(A[k0], Bfr[0][k0], a0, 0, 0, 0);
          a1 = __builtin_amdgcn_mfma_f32_16x16x32_bf16(A[k0], Bfr[1][k0], a1, 0, 0, 0);
          a2 = __builtin_amdgcn_mfma_f32_16x16x32_bf16(A[k0], Bfr[2][k0], a2, 0, 0, 0);
          a3 = __builtin_amdgcn_mfma_f32_16x16x32_bf16(A[k0], Bfr[3][k0], a3, 0, 0, 0);
        }
        // store partials: pg[(wv*4+g)*16 + m][q*4 + r] ; D row = q*4+r (batch), col = m (e)
        *(f32x4_t*)&pg[((wv * 4 + 0) * BSZ + m) * PPITCH + q * 4] = a0;
        *(f32x4_t*)&pg[((wv * 4 + 1) * BSZ + m) * PPITCH + q * 4] = a1;
        *(f32x4_t*)&pg[((wv * 4 + 2) * BSZ + m) * PPITCH + q * 4] = a2;
        *(f32x4_t*)&pg[((wv * 4 + 3) * BSZ + m) * PPITCH + q * 4] = a3;
      }
      __syncthreads();

      // Elementwise LSTM update: one (bb, el) per thread; reduce 4 K-partials
      {
        float gv[NGG];
        #pragma unroll
        for (int g = 0; g < NGG; ++g) {
          gv[g] = pg[((0 * 4 + g) * BSZ + el) * PPITCH + bb]
                + pg[((1 * 4 + g) * BSZ + el) * PPITCH + bb]
                + pg[((2 * 4 + g) * BSZ + el) * PPITCH + bb]
                + pg[((3 * 4 + g) * BSZ + el) * PPITCH + bb];
        }
        const float gi = gv[0] + wxv0 + bias[0];
        const float gf = gv[1] + wxv1 + bias[1];
        const float gz = gv[2] + wxv2 + bias[2];
        const float go = gv[3] + wxv3 + bias[3];
        const float iv = 1.f / (1.f + __expf(-gi));
        const float fv = 1.f / (1.f + __expf(-gf));
        const float zv = tanhf(gz);
        const float ov = 1.f / (1.f + __expf(-go));
        const float cnew = fv * c + iv * zv;
        const float hnew = ov * tanhf(cnew);
        c = cnew;
        hdst[bb * DHH + e0 + el] = f2bf(hnew);
        if (layer == 1) {
          out[((size_t)(t * 2 + 0) * BSZ + bb) * DHH + e0 + el] = hnew;
          out[((size_t)(t * 2 + 1) * BSZ + bb) * DHH + e0 + el] = cnew;
          if (t == TT - 1) {
            const size_t HS = (size_t)TT * 2 * BSZ * DHH;
            out[HS + (0 * BSZ + bb) * DHH + e0 + el] = hnew;                 // last_h
            out[HS + (1 * BSZ + bb) * DHH + e0 + el] = cnew;
            out[HS + 2 * BSZ * DHH + (0 * BSZ + bb) * DHH + e0 + el] = hnew; // out (dup)
            out[HS + 2 * BSZ * DHH + (1 * BSZ + bb) * DHH + e0 + el] = cnew;
          }
        }
      }

      // Inter-WG barrier: syncthreads drains stores to L2; release RMW flushes L2 to
      // the coherent point; acquire fence invalidates before next step's hbuf reads.
      target += NWG;
      __syncthreads();
      if (wv == 0) {
        if (lane == 0)
          __hip_atomic_fetch_add(&cnt[(blockIdx.x & 3) * 32], 1, __ATOMIC_RELEASE, __HIP_MEMORY_SCOPE_AGENT);
        int total = 0;
        do {
          int v = (lane < 4) ? __hip_atomic_load(&cnt[lane * 32], __ATOMIC_RELAXED, __HIP_MEMORY_SCOPE_AGENT) : 0;
          v += __shfl_xor(v, 1);
          v += __shfl_xor(v, 2);
          total = __shfl(v, 0);
        } while (total < target);
        __builtin_amdgcn_fence(__ATOMIC_ACQUIRE, "agent");
      }
      __syncthreads();
    }
  }
}

extern "C" void kernel_launch(void* const* d_in, const int* in_sizes, int n_in,
                              void* d_out, int out_size, void* d_ws, size_t ws_size,
                              hipStream_t stream) {
  const float* states = (const float*)d_in[0];
  const float* Wx0    = (const float*)d_in[1];
  const float* R0     = (const float*)d_in[2];
  const float* b0     = (const float*)d_in[3];
  const float* Wx1    = (const float*)d_in[4];
  const float* R1     = (const float*)d_in[5];
  const float* b1     = (const float*)d_in[6];
  float* out = (float*)d_out;

  int* cnt = (int*)d_ws;
  unsigned short* hbuf = (unsigned short*)((char*)d_ws + 512);  // [2][16*768] bf16

  lstm_init_ws<<<dim3(1), dim3(64), 0, stream>>>(cnt);
  lstm_persistent<<<dim3(NWG), dim3(256), 0, stream>>>(
      states, Wx0, R0, b0, Wx1, R1, b1, out, cnt, hbuf);
}